// Round 10
// baseline (86.704 us; speedup 1.0000x reference)
//
#include <hip/hip_runtime.h>
#include <math.h>

#define B_    4
#define CIN_  64
#define COUT_ 64
#define N_    32768
#define S_    8192

typedef __attribute__((ext_vector_type(8))) short short8;
typedef __attribute__((ext_vector_type(4))) float f32x4a;

static __device__ __forceinline__ unsigned short f2bf(float x) {
    unsigned u = __float_as_uint(x);
    u += 0x7fffu + ((u >> 16) & 1u);
    return (unsigned short)(u >> 16);
}
static __device__ __forceinline__ unsigned pack2bf(float a, float b) {
    return (unsigned)f2bf(a) | ((unsigned)f2bf(b) << 16);
}
template <int CTRL>
static __device__ __forceinline__ float max_ror(float v) {
    float r = __int_as_float(__builtin_amdgcn_update_dpp(
        __float_as_int(v), __float_as_int(v), CTRL, 0xf, 0xf, false));
    return fmaxf(v, r);
}
#define ROR8 0x128
#define ROR4 0x124
#define ROR2 0x122
#define ROR1 0x121

// feats LDS swizzle (unchanged from r9)
static __device__ __forceinline__ int fl(int p, int col) {
    return p * 2048 + (col ^ ((p & 7) << 4) ^ (((col >> 7) & 3) << 5));
}

// ---------------------------------------------------------------------------
// Kernel A1: transpose x [B][64][N] f32 -> xTB [B][N][64] bf16
// ---------------------------------------------------------------------------
__global__ __launch_bounds__(256) void transpose_x_kernel(
    const float* __restrict__ x, unsigned short* __restrict__ xTB)
{
    __shared__ float tile[64][65];
    const int b  = blockIdx.y;
    const int n0 = blockIdx.x * 64;
    const int tx = threadIdx.x & 63;
    const int ty = threadIdx.x >> 6;

    const float* xb = x + (size_t)b * CIN_ * N_;
    #pragma unroll
    for (int c = ty; c < 64; c += 4)
        tile[c][tx] = xb[(size_t)c * N_ + n0 + tx];
    __syncthreads();

    const int cp = threadIdx.x & 31;
    const int r0 = threadIdx.x >> 5;
    unsigned short* xTb = xTB + ((size_t)b * N_ + n0) * 64;
    #pragma unroll
    for (int nn = r0; nn < 64; nn += 8) {
        ushort2 v;
        v.x = f2bf(tile[2 * cp][nn]);
        v.y = f2bf(tile[2 * cp + 1][nn]);
        *(ushort2*)&xTb[(size_t)nn * 64 + 2 * cp] = v;
    }
}

// ---------------------------------------------------------------------------
// Kernel A2: pos [B][3][N] -> posT [B][N][4]
// ---------------------------------------------------------------------------
__global__ __launch_bounds__(256) void post_kernel(
    const float* __restrict__ pos, float* __restrict__ posT)
{
    const int b = blockIdx.y;
    const int n = blockIdx.x * 256 + threadIdx.x;
    const float* pb = pos + (size_t)b * 3 * N_;
    float4 v = make_float4(pb[n], pb[N_ + n], pb[2 * N_ + n], 0.0f);
    *(float4*)&posT[((size_t)b * N_ + n) * 4] = v;
}

// ---------------------------------------------------------------------------
// Kernel A3: wcv f32 [o][c][k] -> wcvB bf16 [o][k*64+c]  (k-major)
// ---------------------------------------------------------------------------
__global__ __launch_bounds__(256) void wcvb_kernel(
    const float* __restrict__ wcv, unsigned short* __restrict__ wcvB)
{
    const int i = blockIdx.x * 256 + threadIdx.x;   // over 64*1024
    const int o   = i >> 10;
    const int rem = i & 1023;
    const int k   = rem >> 6;
    const int c   = rem & 63;
    wcvB[i] = f2bf(wcv[(size_t)o * 1024 + c * 16 + k]);
}

// ---------------------------------------------------------------------------
// Kernel A4: W2/W3 m-part -> MFMA A-fragments (bf16), rows m>=16 zeroed.
// wfr[which][lane][j]: lane (hi,l15): A[k=l15][m=hi*8+j], zero for m>=16.
// ---------------------------------------------------------------------------
__global__ __launch_bounds__(128) void wfrag_kernel(
    const float* __restrict__ w2, const float* __restrict__ w3,
    unsigned short* __restrict__ wfr)
{
    const int t = threadIdx.x;          // 0..127
    const int l = t & 63;
    const float* w = (t >> 6) ? w3 : w2;
    const int row = l & 15, hi = l >> 4;
    #pragma unroll
    for (int j = 0; j < 8; ++j) {
        const int m = hi * 8 + j;
        wfr[t * 8 + j] = (m < 16) ? f2bf(w[row * 32 + m]) : (unsigned short)0;
    }
}

// ---------------------------------------------------------------------------
// Fused kernel: 512 threads, 16 points (2 per wave; all fc exchange wave-local)
//   phase 1: fc1 scalar; fc2/fc3 via 16x16x32 bf16 MFMA (K upper half zero);
//            maxpool via DPP; mp-terms via cooperative t2/t3 bias
//   phase 2: feats via MFMA -> swizzled LDS tile
//   phase 3: out[64 x 16] = wcvB . feats^T
// ---------------------------------------------------------------------------
__global__ __launch_bounds__(512) void fka_fused_kernel(
    const float* __restrict__ posT, const float* __restrict__ sup,
    const int*   __restrict__ nbr, const float* __restrict__ radius,
    const float* __restrict__ w1,  const float* __restrict__ w2,
    const float* __restrict__ w3,  const unsigned short* __restrict__ xTB,
    const unsigned short* __restrict__ wcvB,
    const unsigned short* __restrict__ wfr,
    float* __restrict__ out)
{
    __shared__ unsigned short mbuf[16 * 512];     // 16KB: m1/m2 frags -> m3 frags -> pbuf
    __shared__ unsigned short featsL[16 * 1024];  // 32KB swizzled feats tile
    __shared__ int   idxs[16][32];
    __shared__ float t2s[16][16];                 // t2 -> mp2 -> t3 (sequential reuse)

    const int b  = blockIdx.y;
    const int t  = threadIdx.x;
    const int g  = t >> 5;             // point 0..15
    const int n  = t & 31;             // neighbor
    const int s0 = blockIdx.x * 16;
    const int s  = s0 + g;
    const int wv = t >> 6;             // wave 0..7 (points 2wv, 2wv+1)
    const int l  = t & 63;
    const int l15 = l & 15;
    const int hi  = l >> 4;

    // ---- gather + dw ----
    const int raw    = nbr[(((size_t)b * S_ + s) << 5) + n];
    const bool valid = raw > -1;
    const int id     = valid ? raw : 0;

    unsigned long long bal = __ballot(valid);
    unsigned bits = (unsigned)(bal >> (t & 32));
    const float nrm = sqrtf((float)__popc(bits));
    float dw = valid ? (1.0f / fmaxf(nrm, 1e-12f)) : 0.0f;

    const float4 pg = *(const float4*)&posT[((size_t)b * N_ + id) * 4];
    float px = pg.x - sup[(size_t)(b * 3 + 0) * S_ + s];
    float py = pg.y - sup[(size_t)(b * 3 + 1) * S_ + s];
    float pz = pg.z - sup[(size_t)(b * 3 + 2) * S_ + s];
    if (isinf(px)) dw = 0.0f;
    px = (isnan(px) || isinf(px)) ? 0.0f : px;
    py = (isnan(py) || isinf(py)) ? 0.0f : py;
    pz = (isnan(pz) || isinf(pz)) ? 0.0f : pz;
    const float inv_r = 1.0f / radius[0];
    px *= inv_r; py *= inv_r; pz *= inv_r;

    idxs[g][n] = id;

    // ---- fc1 (scalar f32, exact) ----
    float m1[16];
    #pragma unroll
    for (int k = 0; k < 16; ++k) {
        float v = w1[k * 3 + 0] * px + w1[k * 3 + 1] * py + w1[k * 3 + 2] * pz;
        m1[k] = fmaxf(v, 0.0f) * dw;
    }

    // ---- m1 -> bf16 B-frag LDS (wave-local) ----
    const int pp1 = g & 1, cg1 = n >> 4, col1 = n & 15;
    {
        const int base = wv * 1024 + pp1 * 512 + cg1 * 256;
        const int swz  = ((col1 >> 2) & 3) << 3;
        uint4 u0, u1;
        u0.x = pack2bf(m1[0],  m1[1]);  u0.y = pack2bf(m1[2],  m1[3]);
        u0.z = pack2bf(m1[4],  m1[5]);  u0.w = pack2bf(m1[6],  m1[7]);
        u1.x = pack2bf(m1[8],  m1[9]);  u1.y = pack2bf(m1[10], m1[11]);
        u1.z = pack2bf(m1[12], m1[13]); u1.w = pack2bf(m1[14], m1[15]);
        *(uint4*)&mbuf[base + ((col1 * 16 + 0) ^ swz)] = u0;
        *(uint4*)&mbuf[base + ((col1 * 16 + 8) ^ swz)] = u1;
    }

    // ---- mp1 (f32, exact): shfl xor16 + DPP ror within 16 ----
    float mp1[16];
    #pragma unroll
    for (int k = 0; k < 16; ++k) {
        float v = m1[k];
        v = fmaxf(v, __shfl_xor(v, 16, 32));
        v = max_ror<ROR8>(v); v = max_ror<ROR4>(v);
        v = max_ror<ROR2>(v); v = max_ror<ROR1>(v);
        mp1[k] = v;
    }

    // ---- t2 cooperative bias (f32, exact) ----
    const int kk = n & 15;
    {
        const float* wb = &w2[kk * 32 + 16];
        float pa = 0.0f, pb = 0.0f;
        #pragma unroll
        for (int j = 0; j < 8; ++j) pa = fmaf(wb[j], mp1[j], pa);
        #pragma unroll
        for (int j = 0; j < 8; ++j) pb = fmaf(wb[8 + j], mp1[8 + j], pb);
        float tp = (n & 16) ? pb : pa;
        tp += __shfl_xor(tp, 16, 32);
        t2s[g][kk] = tp;
    }

    // ---- load W A-frags (m>=16 rows are zero) ----
    const short8 aW2 = *(const short8*)(wfr + l * 8);
    const short8 aW3 = *(const short8*)(wfr + 512 + l * 8);
    const int swzr = ((l15 >> 2) & 3) << 3;

    // ---- fc2 via MFMA: 4 groups (pp,cg); C-frag -> m2 -> bf16 B-frag ----
    float mpm[2][4] = {{0.f,0.f,0.f,0.f},{0.f,0.f,0.f,0.f}};
    #pragma unroll
    for (int q = 0; q < 4; ++q) {
        const int pp = q >> 1, cg = q & 1;
        const int base = wv * 1024 + pp * 512 + cg * 256;
        short8 bf = (short8){0,0,0,0,0,0,0,0};
        if (hi < 2)
            bf = *(const short8*)&mbuf[base + ((l15 * 16 + hi * 8) ^ swzr)];
        f32x4a c = (f32x4a){0.f, 0.f, 0.f, 0.f};
        c = __builtin_amdgcn_mfma_f32_16x16x32_bf16(aW2, bf, c, 0, 0, 0);
        const float  dwq = __shfl(dw, pp * 32 + cg * 16 + l15, 64);
        const float4 t2v = *(const float4*)&t2s[2 * wv + pp][hi * 4];
        const float v0 = fmaxf(c[0] + t2v.x, 0.f) * dwq;
        const float v1 = fmaxf(c[1] + t2v.y, 0.f) * dwq;
        const float v2 = fmaxf(c[2] + t2v.z, 0.f) * dwq;
        const float v3 = fmaxf(c[3] + t2v.w, 0.f) * dwq;
        mpm[pp][0] = fmaxf(mpm[pp][0], v0);
        mpm[pp][1] = fmaxf(mpm[pp][1], v1);
        mpm[pp][2] = fmaxf(mpm[pp][2], v2);
        mpm[pp][3] = fmaxf(mpm[pp][3], v3);
        uint2 wval;
        wval.x = pack2bf(v0, v1); wval.y = pack2bf(v2, v3);
        *(uint2*)&mbuf[base + ((l15 * 16 + hi * 4) ^ swzr)] = wval;
    }

    // ---- mp2: DPP ror reduce over the 16 cols (cg already folded) ----
    #pragma unroll
    for (int pp = 0; pp < 2; ++pp)
        #pragma unroll
        for (int r = 0; r < 4; ++r) {
            float v = mpm[pp][r];
            v = max_ror<ROR8>(v); v = max_ror<ROR4>(v);
            v = max_ror<ROR2>(v); v = max_ror<ROR1>(v);
            mpm[pp][r] = v;
        }
    if (l15 == 0) {
        *(float4*)&t2s[2 * wv + 0][hi * 4] =
            make_float4(mpm[0][0], mpm[0][1], mpm[0][2], mpm[0][3]);
        *(float4*)&t2s[2 * wv + 1][hi * 4] =
            make_float4(mpm[1][0], mpm[1][1], mpm[1][2], mpm[1][3]);
    }

    // ---- t3 cooperative bias (reads mp2 from t2s, overwrites with t3) ----
    {
        const int pz = l >> 5;
        const float4 ma  = *(const float4*)&t2s[2 * wv + pz][0];
        const float4 mb2 = *(const float4*)&t2s[2 * wv + pz][4];
        const float4 mc  = *(const float4*)&t2s[2 * wv + pz][8];
        const float4 md  = *(const float4*)&t2s[2 * wv + pz][12];
        const float mp2v[16] = {ma.x, ma.y, ma.z, ma.w, mb2.x, mb2.y, mb2.z, mb2.w,
                                mc.x, mc.y, mc.z, mc.w, md.x, md.y, md.z, md.w};
        const float* wb3 = &w3[(l & 15) * 32 + 16];
        float t3 = 0.0f;
        #pragma unroll
        for (int m = 0; m < 16; ++m) t3 = fmaf(wb3[m], mp2v[m], t3);
        t2s[2 * wv + pz][l & 15] = t3;
    }

    // ---- fc3 via MFMA; m3 written straight into phase-2 B-frag layout ----
    #pragma unroll
    for (int q = 0; q < 4; ++q) {
        const int pp = q >> 1, cg = q & 1;
        const int p  = 2 * wv + pp;
        const int base = wv * 1024 + pp * 512 + cg * 256;
        short8 bf = (short8){0,0,0,0,0,0,0,0};
        if (hi < 2)
            bf = *(const short8*)&mbuf[base + ((l15 * 16 + hi * 8) ^ swzr)];
        f32x4a c = (f32x4a){0.f, 0.f, 0.f, 0.f};
        c = __builtin_amdgcn_mfma_f32_16x16x32_bf16(aW3, bf, c, 0, 0, 0);
        const float  dwq = __shfl(dw, pp * 32 + cg * 16 + l15, 64);
        const float4 t3v = *(const float4*)&t2s[p][hi * 4];
        const float v0 = fmaxf(c[0] + t3v.x, 0.f) * dwq;
        const float v1 = fmaxf(c[1] + t3v.y, 0.f) * dwq;
        const float v2 = fmaxf(c[2] + t3v.z, 0.f) * dwq;
        const float v3 = fmaxf(c[3] + t3v.w, 0.f) * dwq;
        const int nn = cg * 16 + l15;
        const int hh = nn >> 3, jj = nn & 7;
        unsigned short* wb = &mbuf[p * 512 + hh * 128 + jj];
        wb[(((hi * 4 + 0) + hh + p) & 15) * 8] = f2bf(v0);
        wb[(((hi * 4 + 1) + hh + p) & 15) * 8] = f2bf(v1);
        wb[(((hi * 4 + 2) + hh + p) & 15) * 8] = f2bf(v2);
        wb[(((hi * 4 + 3) + hh + p) & 15) * 8] = f2bf(v3);
    }
    // everything above is wave-local -> no barrier before phase 2

    // ---- phase 2: feats via MFMA (2 points per wave) -> swizzled LDS ----
    const int hi2 = hi;
    const int k15 = l15;
    const unsigned short* xb = xTB + (size_t)b * N_ * 64;
    char* fLp = (char*)featsL;

    for (int pp = 0; pp < 2; ++pp) {
        const int p = wv * 2 + pp;

        int ids8[8];
        #pragma unroll
        for (int j = 0; j < 8; ++j) ids8[j] = idxs[p][hi2 * 8 + j];

        const int brow = (k15 + hi2 + p) & 15;
        short8 bfrag = *(const short8*)&mbuf[p * 512 + hi2 * 128 + brow * 8];

        f32x4a acc[4];
        #pragma unroll
        for (int ct = 0; ct < 4; ++ct) acc[ct] = (f32x4a){0.f, 0.f, 0.f, 0.f};

        #pragma unroll
        for (int ct = 0; ct < 4; ++ct) {
            union { unsigned short u[8]; short8 v; } A;
            #pragma unroll
            for (int j = 0; j < 8; ++j)
                A.u[j] = xb[((size_t)ids8[j] << 6) + ct * 16 + k15];
            acc[ct] = __builtin_amdgcn_mfma_f32_16x16x32_bf16(A.v, bfrag, acc[ct], 0, 0, 0);
        }

        #pragma unroll
        for (int ct = 0; ct < 4; ++ct) {
            uint2 val;
            val.x = pack2bf(acc[ct][0], acc[ct][1]);
            val.y = pack2bf(acc[ct][2], acc[ct][3]);
            const int col = k15 * 128 + ct * 32 + hi2 * 8;
            *(uint2*)(fLp + fl(p, col)) = val;
        }
    }
    __syncthreads();

    // ---- phase 3: out tile 64 x 16. wave = (o-tile 0..3, k-half 0..1) ----
    const int ot = wv & 3;
    const int kh = wv >> 2;
    const int lq = hi2;

    const unsigned short* apod =
        wcvB + (size_t)(ot * 16 + l15) * 1024 + kh * 512 + lq * 8;

    f32x4a oacc = (f32x4a){0.f, 0.f, 0.f, 0.f};
    #pragma unroll 4
    for (int ks = 0; ks < 16; ++ks) {
        const int col = kh * 1024 + ks * 64 + lq * 16;
        short8 bfv = *(const short8*)(fLp + fl(l15, col));
        short8 afv = *(const short8*)(apod + ks * 32);
        oacc = __builtin_amdgcn_mfma_f32_16x16x32_bf16(afv, bfv, oacc, 0, 0, 0);
    }

    float* pbuf = (float*)mbuf;    // 4 tiles x 256 floats = 4KB
    if (kh == 1) {
        #pragma unroll
        for (int r = 0; r < 4; ++r)
            pbuf[ot * 256 + (lq * 4 + r) * 16 + l15] = oacc[r];
    }
    __syncthreads();
    if (kh == 0) {
        const int sidx = s0 + l15;
        const bool infs = isinf(sup[(size_t)b * 3 * S_ + sidx]);
        #pragma unroll
        for (int r = 0; r < 4; ++r) {
            const float v = oacc[r] + pbuf[ot * 256 + (lq * 4 + r) * 16 + l15];
            const int o = ot * 16 + lq * 4 + r;
            out[((size_t)b * COUT_ + o) * S_ + sidx] = infs ? INFINITY : v;
        }
    }
}

// ---------------------------------------------------------------------------
extern "C" void kernel_launch(void* const* d_in, const int* in_sizes, int n_in,
                              void* d_out, int out_size, void* d_ws, size_t ws_size,
                              hipStream_t stream)
{
    const float* x   = (const float*)d_in[0];
    const float* pos = (const float*)d_in[1];
    const float* sup = (const float*)d_in[2];
    const int*   nbr = (const int*)d_in[3];
    const float* rad = (const float*)d_in[4];
    const float* w1  = (const float*)d_in[5];
    const float* w2  = (const float*)d_in[6];
    const float* w3  = (const float*)d_in[7];
    const float* wcv = (const float*)d_in[8];
    float* out = (float*)d_out;

    char* p = (char*)d_ws;
    unsigned short* xTB = (unsigned short*)p;  p += (size_t)B_ * N_ * 64 * sizeof(unsigned short);
    float* posT = (float*)p;                   p += (size_t)B_ * N_ * 4 * sizeof(float);
    unsigned short* wcvB = (unsigned short*)p; p += (size_t)COUT_ * 1024 * sizeof(unsigned short);
    unsigned short* wfr = (unsigned short*)p;  p += (size_t)2 * 64 * 8 * sizeof(unsigned short);

    transpose_x_kernel<<<dim3(N_ / 64, B_), 256, 0, stream>>>(x, xTB);
    post_kernel<<<dim3(N_ / 256, B_), 256, 0, stream>>>(pos, posT);
    wcvb_kernel<<<dim3(256), 256, 0, stream>>>(wcv, wcvB);
    wfrag_kernel<<<dim3(1), 128, 0, stream>>>(w2, w3, wfr);

    fka_fused_kernel<<<dim3(S_ / 16, B_), 512, 0, stream>>>(
        posT, sup, nbr, rad, w1, w2, w3, xTB, wcvB, wfr, out);
}

// Round 11
// 80.654 us; speedup vs baseline: 1.0750x; 1.0750x over previous
//
#include <hip/hip_runtime.h>
#include <math.h>

#define B_    4
#define CIN_  64
#define COUT_ 64
#define N_    32768
#define S_    8192

typedef __attribute__((ext_vector_type(8))) short short8;
typedef __attribute__((ext_vector_type(4))) float f32x4a;

static __device__ __forceinline__ unsigned short f2bf(float x) {
    unsigned u = __float_as_uint(x);
    u += 0x7fffu + ((u >> 16) & 1u);
    return (unsigned short)(u >> 16);
}
static __device__ __forceinline__ unsigned pack2bf(float a, float b) {
    return (unsigned)f2bf(a) | ((unsigned)f2bf(b) << 16);
}
template <int CTRL>
static __device__ __forceinline__ float max_ror(float v) {
    float r = __int_as_float(__builtin_amdgcn_update_dpp(
        __float_as_int(v), __float_as_int(v), CTRL, 0xf, 0xf, false));
    return fmaxf(v, r);
}
#define ROR8 0x128
#define ROR4 0x124
#define ROR2 0x122
#define ROR1 0x121

// feats LDS swizzle: row p (2048B rows), col = byte offset within row.
static __device__ __forceinline__ int fl(int p, int col) {
    return p * 2048 + (col ^ ((p & 7) << 4) ^ (((col >> 7) & 3) << 5));
}

// ---------------------------------------------------------------------------
// Kernel A1: transpose x [B][64][N] f32 -> xTB [B][N][64] bf16
// ---------------------------------------------------------------------------
__global__ __launch_bounds__(256) void transpose_x_kernel(
    const float* __restrict__ x, unsigned short* __restrict__ xTB)
{
    __shared__ float tile[64][65];
    const int b  = blockIdx.y;
    const int n0 = blockIdx.x * 64;
    const int tx = threadIdx.x & 63;
    const int ty = threadIdx.x >> 6;

    const float* xb = x + (size_t)b * CIN_ * N_;
    #pragma unroll
    for (int c = ty; c < 64; c += 4)
        tile[c][tx] = xb[(size_t)c * N_ + n0 + tx];
    __syncthreads();

    const int cp = threadIdx.x & 31;
    const int r0 = threadIdx.x >> 5;
    unsigned short* xTb = xTB + ((size_t)b * N_ + n0) * 64;
    #pragma unroll
    for (int nn = r0; nn < 64; nn += 8) {
        ushort2 v;
        v.x = f2bf(tile[2 * cp][nn]);
        v.y = f2bf(tile[2 * cp + 1][nn]);
        *(ushort2*)&xTb[(size_t)nn * 64 + 2 * cp] = v;
    }
}

// ---------------------------------------------------------------------------
// Kernel A2: pos [B][3][N] -> posT [B][N][4]
// ---------------------------------------------------------------------------
__global__ __launch_bounds__(256) void post_kernel(
    const float* __restrict__ pos, float* __restrict__ posT)
{
    const int b = blockIdx.y;
    const int n = blockIdx.x * 256 + threadIdx.x;
    const float* pb = pos + (size_t)b * 3 * N_;
    float4 v = make_float4(pb[n], pb[N_ + n], pb[2 * N_ + n], 0.0f);
    *(float4*)&posT[((size_t)b * N_ + n) * 4] = v;
}

// ---------------------------------------------------------------------------
// Kernel A3: wcv f32 [o][c][k] -> wcvB bf16 [o][k*64+c]  (k-major)
// ---------------------------------------------------------------------------
__global__ __launch_bounds__(256) void wcvb_kernel(
    const float* __restrict__ wcv, unsigned short* __restrict__ wcvB)
{
    const int i = blockIdx.x * 256 + threadIdx.x;   // over 64*1024
    const int o   = i >> 10;
    const int rem = i & 1023;
    const int k   = rem >> 6;
    const int c   = rem & 63;
    wcvB[i] = f2bf(wcv[(size_t)o * 1024 + c * 16 + k]);
}

// ---------------------------------------------------------------------------
// Fused kernel: 512 threads, 16 points.
//   phase 1: fc pipeline (lane = neighbor); m3 frag written into the ALIASED
//            head of this point's own featsL row (wave-local, no barrier)
//   phase 2: per wave, read own 2 B-frags to regs FIRST, then gather+MFMA,
//            write feats over the full row (clobbers alias, safely)
//   phase 3: out[64 x 16] = wcvB . feats^T  (after the single barrier)
// LDS = 32K featsL + 2K idxs + 1K t2s + 4K pbuf = 39K -> 4 blocks/CU.
// ---------------------------------------------------------------------------
__global__ __launch_bounds__(512) void fka_fused_kernel(
    const float* __restrict__ posT, const float* __restrict__ sup,
    const int*   __restrict__ nbr, const float* __restrict__ radius,
    const float* __restrict__ w1,  const float* __restrict__ w2,
    const float* __restrict__ w3,  const unsigned short* __restrict__ xTB,
    const unsigned short* __restrict__ wcvB,
    float* __restrict__ out)
{
    __shared__ unsigned short featsL[16 * 1024];  // 32KB; head of row p aliases m3 frag of point p
    __shared__ int   idxs[16][32];
    __shared__ float t2s[16][16];
    __shared__ float pbuf[1024];                  // 4KB phase-3 partials

    const int b  = blockIdx.y;
    const int t  = threadIdx.x;
    const int g  = t >> 5;             // point group 0..15
    const int n  = t & 31;
    const int s0 = blockIdx.x * 16;
    const int s  = s0 + g;

    // ---- phase 1: fc pipeline (lane = neighbor), scalar f32 ----
    const int raw    = nbr[(((size_t)b * S_ + s) << 5) + n];
    const bool valid = raw > -1;
    const int id     = valid ? raw : 0;

    unsigned long long bal = __ballot(valid);
    unsigned bits = (unsigned)(bal >> (t & 32));
    const float nrm = sqrtf((float)__popc(bits));
    float dw = valid ? (1.0f / fmaxf(nrm, 1e-12f)) : 0.0f;

    const float4 pg = *(const float4*)&posT[((size_t)b * N_ + id) * 4];
    float px = pg.x - sup[(size_t)(b * 3 + 0) * S_ + s];
    float py = pg.y - sup[(size_t)(b * 3 + 1) * S_ + s];
    float pz = pg.z - sup[(size_t)(b * 3 + 2) * S_ + s];
    if (isinf(px)) dw = 0.0f;
    px = (isnan(px) || isinf(px)) ? 0.0f : px;
    py = (isnan(py) || isinf(py)) ? 0.0f : py;
    pz = (isnan(pz) || isinf(pz)) ? 0.0f : pz;
    const float inv_r = 1.0f / radius[0];
    px *= inv_r; py *= inv_r; pz *= inv_r;

    const int kk = n & 15;

    float m1[16], mp1[16], m2[16], mp2[16], m3[16];

    #pragma unroll
    for (int k = 0; k < 16; ++k) {
        float v = w1[k * 3 + 0] * px + w1[k * 3 + 1] * py + w1[k * 3 + 2] * pz;
        m1[k] = fmaxf(v, 0.0f) * dw;
    }
    #pragma unroll
    for (int k = 0; k < 16; ++k) {
        float v = m1[k];
        v = fmaxf(v, __shfl_xor(v, 16, 32));
        v = max_ror<ROR8>(v); v = max_ror<ROR4>(v);
        v = max_ror<ROR2>(v); v = max_ror<ROR1>(v);
        mp1[k] = v;
    }
    {
        const float* wb = &w2[kk * 32 + 16];
        float pa = 0.0f, pb = 0.0f;
        #pragma unroll
        for (int j = 0; j < 8; ++j) pa = fmaf(wb[j], mp1[j], pa);
        #pragma unroll
        for (int j = 0; j < 8; ++j) pb = fmaf(wb[8 + j], mp1[8 + j], pb);
        float tp = (n & 16) ? pb : pa;
        tp += __shfl_xor(tp, 16, 32);
        t2s[g][kk] = tp;
    }
    {
        float4 ta = *(const float4*)&t2s[g][0];
        float4 tb = *(const float4*)&t2s[g][4];
        float4 tc = *(const float4*)&t2s[g][8];
        float4 td = *(const float4*)&t2s[g][12];
        float t2v[16] = {ta.x, ta.y, ta.z, ta.w, tb.x, tb.y, tb.z, tb.w,
                         tc.x, tc.y, tc.z, tc.w, td.x, td.y, td.z, td.w};
        #pragma unroll
        for (int k = 0; k < 16; ++k) {
            const float* wr = &w2[k * 32];
            float v = t2v[k];
            #pragma unroll
            for (int j = 0; j < 16; ++j) v = fmaf(wr[j], m1[j], v);
            m2[k] = fmaxf(v, 0.0f) * dw;
        }
    }
    #pragma unroll
    for (int k = 0; k < 16; ++k) {
        float v = m2[k];
        v = fmaxf(v, __shfl_xor(v, 16, 32));
        v = max_ror<ROR8>(v); v = max_ror<ROR4>(v);
        v = max_ror<ROR2>(v); v = max_ror<ROR1>(v);
        mp2[k] = v;
    }
    {
        const float* wb = &w3[kk * 32 + 16];
        float pa = 0.0f, pb = 0.0f;
        #pragma unroll
        for (int j = 0; j < 8; ++j) pa = fmaf(wb[j], mp2[j], pa);
        #pragma unroll
        for (int j = 0; j < 8; ++j) pb = fmaf(wb[8 + j], mp2[8 + j], pb);
        float tp = (n & 16) ? pb : pa;
        tp += __shfl_xor(tp, 16, 32);
        t2s[g][kk] = tp;
    }
    {
        float4 ta = *(const float4*)&t2s[g][0];
        float4 tb = *(const float4*)&t2s[g][4];
        float4 tc = *(const float4*)&t2s[g][8];
        float4 td = *(const float4*)&t2s[g][12];
        float t3v[16] = {ta.x, ta.y, ta.z, ta.w, tb.x, tb.y, tb.z, tb.w,
                         tc.x, tc.y, tc.z, tc.w, td.x, td.y, td.z, td.w};
        #pragma unroll
        for (int k = 0; k < 16; ++k) {
            const float* wr = &w3[k * 32];
            float v = t3v[k];
            #pragma unroll
            for (int j = 0; j < 16; ++j) v = fmaf(wr[j], m2[j], v);
            m3[k] = fmaxf(v, 0.0f) * dw;
        }
    }

    idxs[g][n] = id;
    {
        // m3 B-frag aliased into head of featsL row g (offsets < 512 ushorts)
        const int hi = n >> 3, jj = n & 7;
        unsigned short* base = &featsL[g * 1024 + hi * 128 + jj];
        #pragma unroll
        for (int k = 0; k < 16; ++k) {
            const int row = (k + hi + g) & 15;
            base[row * 8] = f2bf(m3[k]);
        }
    }
    // all of the above is wave-local (p = 2wv, 2wv+1) -> NO barrier here

    // ---- phase 2: feats via MFMA (2 points per wave) -> swizzled LDS ----
    const int wv  = t >> 6;
    const int l   = t & 63;
    const int hi2 = l >> 4;
    const int k15 = l & 15;
    const unsigned short* xb = xTB + (size_t)b * N_ * 64;
    char* fLp = (char*)featsL;

    // read BOTH B-frags from the aliased region before any featsL write
    short8 bfrag[2];
    #pragma unroll
    for (int pp = 0; pp < 2; ++pp) {
        const int p = wv * 2 + pp;
        const int brow = (k15 + hi2 + p) & 15;
        bfrag[pp] = *(const short8*)&featsL[p * 1024 + hi2 * 128 + brow * 8];
    }

    #pragma unroll
    for (int pp = 0; pp < 2; ++pp) {
        const int p = wv * 2 + pp;

        int ids8[8];
        #pragma unroll
        for (int j = 0; j < 8; ++j) ids8[j] = idxs[p][hi2 * 8 + j];

        f32x4a acc[4];
        #pragma unroll
        for (int ct = 0; ct < 4; ++ct) acc[ct] = (f32x4a){0.f, 0.f, 0.f, 0.f};

        #pragma unroll
        for (int ct = 0; ct < 4; ++ct) {
            union { unsigned short u[8]; short8 v; } A;
            #pragma unroll
            for (int j = 0; j < 8; ++j)
                A.u[j] = xb[((size_t)ids8[j] << 6) + ct * 16 + k15];
            acc[ct] = __builtin_amdgcn_mfma_f32_16x16x32_bf16(A.v, bfrag[pp], acc[ct], 0, 0, 0);
        }

        // acc[ct][r] = feats[c = ct*16 + hi2*4 + r][k = k15]; k-major idx = k*64+c
        #pragma unroll
        for (int ct = 0; ct < 4; ++ct) {
            uint2 val;
            val.x = pack2bf(acc[ct][0], acc[ct][1]);
            val.y = pack2bf(acc[ct][2], acc[ct][3]);
            const int col = k15 * 128 + ct * 32 + hi2 * 8;
            *(uint2*)(fLp + fl(p, col)) = val;   // own row only (p = 2wv+pp)
        }
    }
    __syncthreads();

    // ---- phase 3: out tile 64 x 16. wave = (o-tile 0..3, k-half 0..1) ----
    const int ot  = wv & 3;
    const int kh  = wv >> 2;
    const int lq  = hi2;
    const int l15 = k15;

    const unsigned short* apod =
        wcvB + (size_t)(ot * 16 + l15) * 1024 + kh * 512 + lq * 8;

    f32x4a oacc = (f32x4a){0.f, 0.f, 0.f, 0.f};
    #pragma unroll 4
    for (int ks = 0; ks < 16; ++ks) {
        const int col = kh * 1024 + ks * 64 + lq * 16;
        short8 bfv = *(const short8*)(fLp + fl(l15, col));
        short8 afv = *(const short8*)(apod + ks * 32);
        oacc = __builtin_amdgcn_mfma_f32_16x16x32_bf16(afv, bfv, oacc, 0, 0, 0);
    }

    if (kh == 1) {
        #pragma unroll
        for (int r = 0; r < 4; ++r)
            pbuf[ot * 256 + (lq * 4 + r) * 16 + l15] = oacc[r];
    }
    __syncthreads();
    if (kh == 0) {
        const int sidx = s0 + l15;
        const bool infs = isinf(sup[(size_t)b * 3 * S_ + sidx]);
        #pragma unroll
        for (int r = 0; r < 4; ++r) {
            const float v = oacc[r] + pbuf[ot * 256 + (lq * 4 + r) * 16 + l15];
            const int o = ot * 16 + lq * 4 + r;
            out[((size_t)b * COUT_ + o) * S_ + sidx] = infs ? INFINITY : v;
        }
    }
}

// ---------------------------------------------------------------------------
extern "C" void kernel_launch(void* const* d_in, const int* in_sizes, int n_in,
                              void* d_out, int out_size, void* d_ws, size_t ws_size,
                              hipStream_t stream)
{
    const float* x   = (const float*)d_in[0];
    const float* pos = (const float*)d_in[1];
    const float* sup = (const float*)d_in[2];
    const int*   nbr = (const int*)d_in[3];
    const float* rad = (const float*)d_in[4];
    const float* w1  = (const float*)d_in[5];
    const float* w2  = (const float*)d_in[6];
    const float* w3  = (const float*)d_in[7];
    const float* wcv = (const float*)d_in[8];
    float* out = (float*)d_out;

    char* p = (char*)d_ws;
    unsigned short* xTB = (unsigned short*)p;  p += (size_t)B_ * N_ * 64 * sizeof(unsigned short);
    float* posT = (float*)p;                   p += (size_t)B_ * N_ * 4 * sizeof(float);
    unsigned short* wcvB = (unsigned short*)p; p += (size_t)COUT_ * 1024 * sizeof(unsigned short);

    transpose_x_kernel<<<dim3(N_ / 64, B_), 256, 0, stream>>>(x, xTB);
    post_kernel<<<dim3(N_ / 256, B_), 256, 0, stream>>>(pos, posT);
    wcvb_kernel<<<dim3(256), 256, 0, stream>>>(wcv, wcvB);

    fka_fused_kernel<<<dim3(S_ / 16, B_), 512, 0, stream>>>(
        posT, sup, nbr, rad, w1, w2, w3, xTB, wcvB, out);
}